// Round 1
// baseline (2931.076 us; speedup 1.0000x reference)
//
#include <hip/hip_runtime.h>

#define D 128

// ---- degree histogram over src ----
__global__ __launch_bounds__(256) void k_degree(const int* __restrict__ src,
                                                int* __restrict__ deg, int n_edges) {
    int e = blockIdx.x * 256 + threadIdx.x;
    if (e < n_edges) atomicAdd(&deg[src[e]], 1);
}

// ---- dis[n] = deg>0 ? rsqrt(deg) : 0 ----
__global__ __launch_bounds__(256) void k_dis(const int* __restrict__ deg,
                                             float* __restrict__ dis, int n) {
    int i = blockIdx.x * 256 + threadIdx.x;
    if (i < n) {
        int d = deg[i];
        dis[i] = (d > 0) ? rsqrtf((float)d) : 0.0f;
    }
}

// ---- h = x @ W, fp32.  64 rows x 128 cols per block, 256 threads, 4x8 micro-tile.
// LDS: W full (64KB) + x tile padded to 132 (33KB) -> ~97KB, 1 block/CU (GEMM is
// ~25us total; scatter dominates, so occupancy here is fine).
__global__ __launch_bounds__(256) void k_gemm(const float* __restrict__ x,
                                              const float* __restrict__ w,
                                              float* __restrict__ h, int nrows) {
    __shared__ float sW[128][128];
    __shared__ float sX[64][132];   // +4 pad: 2-way max bank aliasing (free per m136)
    int tid = threadIdx.x;

    const float4* w4 = (const float4*)w;
    float4* sw4 = (float4*)&sW[0][0];
    #pragma unroll
    for (int i = 0; i < 16; ++i) sw4[tid + 256 * i] = w4[tid + 256 * i];

    int row0 = blockIdx.x * 64;
    int nr = min(64, nrows - row0);
    const float4* x4 = (const float4*)(x + (size_t)row0 * D);
    for (int i = tid; i < nr * 32; i += 256) {
        int r = i >> 5, c = i & 31;
        ((float4*)&sX[r][0])[c] = x4[i];
    }
    __syncthreads();

    int tx = tid & 15;   // col group: 8 cols
    int ty = tid >> 4;   // row group: 4 rows
    float acc[4][8] = {};
    #pragma unroll 4
    for (int k = 0; k < 128; ++k) {
        float a[4];
        #pragma unroll
        for (int r = 0; r < 4; ++r) a[r] = sX[ty * 4 + r][k];
        float4 b0 = *((const float4*)&sW[k][tx * 8]);
        float4 b1 = *((const float4*)&sW[k][tx * 8 + 4]);
        float b[8] = {b0.x, b0.y, b0.z, b0.w, b1.x, b1.y, b1.z, b1.w};
        #pragma unroll
        for (int r = 0; r < 4; ++r)
            #pragma unroll
            for (int c = 0; c < 8; ++c)
                acc[r][c] = fmaf(a[r], b[c], acc[r][c]);
    }

    #pragma unroll
    for (int r = 0; r < 4; ++r) {
        int row = ty * 4 + r;
        if (row < nr) {
            float4* hp = (float4*)(h + (size_t)(row0 + row) * D + tx * 8);
            hp[0] = make_float4(acc[r][0], acc[r][1], acc[r][2], acc[r][3]);
            hp[1] = make_float4(acc[r][4], acc[r][5], acc[r][6], acc[r][7]);
        }
    }
}

// ---- out[i] = bias[i % 128]  (out is re-poisoned before every timed launch) ----
__global__ __launch_bounds__(256) void k_init_out(float* __restrict__ out,
                                                  const float* __restrict__ bias, int n4) {
    int i = blockIdx.x * 256 + threadIdx.x;
    if (i < n4) {
        ((float4*)out)[i] = ((const float4*)bias)[i & 31];
    }
}

// ---- edge scatter: 32 lanes per edge, float4 gather, 4 f32 atomics/lane ----
__global__ __launch_bounds__(256) void k_scatter(const int* __restrict__ src,
                                                 const int* __restrict__ dst,
                                                 const float* __restrict__ dis,
                                                 const float* __restrict__ h,
                                                 float* __restrict__ out, int n_edges) {
    int t = blockIdx.x * 256 + threadIdx.x;
    int e = t >> 5;
    if (e >= n_edges) return;
    int lane = t & 31;
    int s = src[e], d = dst[e];
    float nrm = dis[s] * dis[d];
    float4 hv = ((const float4*)(h + (size_t)s * D))[lane];
    float* op = out + (size_t)d * D + lane * 4;
    atomicAdd(op + 0, nrm * hv.x);
    atomicAdd(op + 1, nrm * hv.y);
    atomicAdd(op + 2, nrm * hv.z);
    atomicAdd(op + 3, nrm * hv.w);
}

extern "C" void kernel_launch(void* const* d_in, const int* in_sizes, int n_in,
                              void* d_out, int out_size, void* d_ws, size_t ws_size,
                              hipStream_t stream) {
    const float* x    = (const float*)d_in[0];
    const int*   ei   = (const int*)d_in[1];   // int32 [2, E]: row0 = src, row1 = dst
    const float* w    = (const float*)d_in[2];
    const float* bias = (const float*)d_in[3];
    float* out = (float*)d_out;

    int n_edges = in_sizes[1] / 2;
    int n_nodes = in_sizes[0] / D;
    const int* src = ei;
    const int* dst = ei + n_edges;

    // workspace layout: h [n_nodes*128 f32] | deg [n_nodes i32] | dis [n_nodes f32]
    char* ws = (char*)d_ws;
    float* h   = (float*)ws;
    int*   deg = (int*)(ws + (size_t)n_nodes * D * sizeof(float));
    float* dis = (float*)(deg + n_nodes);

    hipMemsetAsync(deg, 0, (size_t)n_nodes * sizeof(int), stream);
    k_degree<<<(n_edges + 255) / 256, 256, 0, stream>>>(src, deg, n_edges);
    k_dis<<<(n_nodes + 255) / 256, 256, 0, stream>>>(deg, dis, n_nodes);
    k_gemm<<<(n_nodes + 63) / 64, 256, 0, stream>>>(x, w, h, n_nodes);
    k_init_out<<<(n_nodes * (D / 4) + 255) / 256, 256, 0, stream>>>(out, bias, n_nodes * (D / 4));
    long long total = (long long)n_edges * 32;
    k_scatter<<<(int)((total + 255) / 256), 256, 0, stream>>>(src, dst, dis, h, out, n_edges);
}

// Round 2
// 504.647 us; speedup vs baseline: 5.8082x; 5.8082x over previous
//
#include <hip/hip_runtime.h>

#define D 128

// ---- joint degree histograms: deg_src (for normalization), deg_dst (for CSR) ----
__global__ __launch_bounds__(256) void k_hist(const int* __restrict__ src,
                                              const int* __restrict__ dst,
                                              int* __restrict__ deg_src,
                                              int* __restrict__ deg_dst, int n_edges) {
    int e = blockIdx.x * 256 + threadIdx.x;
    if (e < n_edges) {
        atomicAdd(&deg_src[src[e]], 1);
        atomicAdd(&deg_dst[dst[e]], 1);
    }
}

// ---- dis[n] = deg_src>0 ? rsqrt(deg_src) : 0 ----
__global__ __launch_bounds__(256) void k_dis(const int* __restrict__ deg,
                                             float* __restrict__ dis, int n) {
    int i = blockIdx.x * 256 + threadIdx.x;
    if (i < n) {
        int d = deg[i];
        dis[i] = (d > 0) ? rsqrtf((float)d) : 0.0f;
    }
}

__device__ __forceinline__ int wave_iscan(int v, int lane) {
    #pragma unroll
    for (int off = 1; off < 64; off <<= 1) {
        int t = __shfl_up(v, off, 64);
        if (lane >= off) v += t;
    }
    return v;
}

// ---- scan stage 1: per-block (256 elems) sums ----
__global__ __launch_bounds__(256) void k_bsum(const int* __restrict__ deg,
                                              int* __restrict__ bsum, int n) {
    int i = blockIdx.x * 256 + threadIdx.x;
    int v = (i < n) ? deg[i] : 0;
    #pragma unroll
    for (int off = 32; off > 0; off >>= 1) v += __shfl_down(v, off, 64);
    __shared__ int ws[4];
    int lane = threadIdx.x & 63, wid = threadIdx.x >> 6;
    if (lane == 0) ws[wid] = v;
    __syncthreads();
    if (threadIdx.x == 0) bsum[blockIdx.x] = ws[0] + ws[1] + ws[2] + ws[3];
}

// ---- scan stage 2: exclusive scan of block sums (nb <= 512), one block ----
__global__ __launch_bounds__(512) void k_scanb(int* __restrict__ bsum, int nb) {
    __shared__ int s[512];
    int t = threadIdx.x;
    int v = (t < nb) ? bsum[t] : 0;
    s[t] = v;
    __syncthreads();
    for (int off = 1; off < 512; off <<= 1) {
        int u = (t >= off) ? s[t - off] : 0;
        __syncthreads();
        s[t] += u;
        __syncthreads();
    }
    if (t < nb) bsum[t] = s[t] - v;   // exclusive prefix
}

// ---- scan stage 3: final exclusive scan -> rowptr, cursor ----
__global__ __launch_bounds__(256) void k_scanf(const int* __restrict__ deg,
                                               const int* __restrict__ bsum,
                                               int* __restrict__ rowptr,
                                               int* __restrict__ cursor, int n) {
    int i = blockIdx.x * 256 + threadIdx.x;
    int lane = threadIdx.x & 63, wid = threadIdx.x >> 6;
    int v = (i < n) ? deg[i] : 0;
    int incl = wave_iscan(v, lane);
    __shared__ int ws[4];
    if (lane == 63) ws[wid] = incl;
    __syncthreads();
    int off = bsum[blockIdx.x];
    for (int w = 0; w < wid; ++w) off += ws[w];
    int excl = off + incl - v;
    if (i < n) { rowptr[i] = excl; cursor[i] = excl; }
}

// ---- bucket: place {src, norm} per edge into dst-sorted order ----
__global__ __launch_bounds__(256) void k_bucket(const int* __restrict__ src,
                                                const int* __restrict__ dst,
                                                const float* __restrict__ dis,
                                                int* __restrict__ cursor,
                                                int2* __restrict__ edata, int n_edges) {
    int e = blockIdx.x * 256 + threadIdx.x;
    if (e >= n_edges) return;
    int s = src[e], d = dst[e];
    int pos = atomicAdd(&cursor[d], 1);
    edata[pos] = make_int2(s, __float_as_int(dis[s] * dis[d]));
}

// ---- h = x @ W, fp32.  64 rows x 128 cols per block, 256 threads, 4x8 micro-tile.
__global__ __launch_bounds__(256) void k_gemm(const float* __restrict__ x,
                                              const float* __restrict__ w,
                                              float* __restrict__ h, int nrows) {
    __shared__ float sW[128][128];
    __shared__ float sX[64][132];
    int tid = threadIdx.x;

    const float4* w4 = (const float4*)w;
    float4* sw4 = (float4*)&sW[0][0];
    #pragma unroll
    for (int i = 0; i < 16; ++i) sw4[tid + 256 * i] = w4[tid + 256 * i];

    int row0 = blockIdx.x * 64;
    int nr = min(64, nrows - row0);
    const float4* x4 = (const float4*)(x + (size_t)row0 * D);
    for (int i = tid; i < nr * 32; i += 256) {
        int r = i >> 5, c = i & 31;
        ((float4*)&sX[r][0])[c] = x4[i];
    }
    __syncthreads();

    int tx = tid & 15;
    int ty = tid >> 4;
    float acc[4][8] = {};
    #pragma unroll 4
    for (int k = 0; k < 128; ++k) {
        float a[4];
        #pragma unroll
        for (int r = 0; r < 4; ++r) a[r] = sX[ty * 4 + r][k];
        float4 b0 = *((const float4*)&sW[k][tx * 8]);
        float4 b1 = *((const float4*)&sW[k][tx * 8 + 4]);
        float b[8] = {b0.x, b0.y, b0.z, b0.w, b1.x, b1.y, b1.z, b1.w};
        #pragma unroll
        for (int r = 0; r < 4; ++r)
            #pragma unroll
            for (int c = 0; c < 8; ++c)
                acc[r][c] = fmaf(a[r], b[c], acc[r][c]);
    }

    #pragma unroll
    for (int r = 0; r < 4; ++r) {
        int row = ty * 4 + r;
        if (row < nr) {
            float4* hp = (float4*)(h + (size_t)(row0 + row) * D + tx * 8);
            hp[0] = make_float4(acc[r][0], acc[r][1], acc[r][2], acc[r][3]);
            hp[1] = make_float4(acc[r][4], acc[r][5], acc[r][6], acc[r][7]);
        }
    }
}

// ---- accumulate: one wave per node, lane owns float2 of the row; no atomics ----
__global__ __launch_bounds__(256) void k_accum(const int2* __restrict__ edata,
                                               const int* __restrict__ rowptr,
                                               const int* __restrict__ degd,
                                               const float* __restrict__ h,
                                               const float* __restrict__ bias,
                                               float* __restrict__ out, int n) {
    int wid = threadIdx.x >> 6, lane = threadIdx.x & 63;
    int node = blockIdx.x * 4 + wid;
    if (node >= n) return;
    int start = rowptr[node];
    int deg = degd[node];
    float2 acc = make_float2(0.0f, 0.0f);
    int e = 0;
    // 2-edge unroll: overlap the two dependent (edata -> h) load chains
    for (; e + 1 < deg; e += 2) {
        int2 e0 = edata[start + e];
        int2 e1 = edata[start + e + 1];
        float2 h0 = *((const float2*)(h + (size_t)e0.x * D) + lane);
        float2 h1 = *((const float2*)(h + (size_t)e1.x * D) + lane);
        float n0 = __int_as_float(e0.y), n1 = __int_as_float(e1.y);
        acc.x = fmaf(n0, h0.x, acc.x); acc.y = fmaf(n0, h0.y, acc.y);
        acc.x = fmaf(n1, h1.x, acc.x); acc.y = fmaf(n1, h1.y, acc.y);
    }
    if (e < deg) {
        int2 e0 = edata[start + e];
        float2 h0 = *((const float2*)(h + (size_t)e0.x * D) + lane);
        float n0 = __int_as_float(e0.y);
        acc.x = fmaf(n0, h0.x, acc.x); acc.y = fmaf(n0, h0.y, acc.y);
    }
    float2 b = ((const float2*)bias)[lane];
    ((float2*)(out + (size_t)node * D))[lane] = make_float2(acc.x + b.x, acc.y + b.y);
}

extern "C" void kernel_launch(void* const* d_in, const int* in_sizes, int n_in,
                              void* d_out, int out_size, void* d_ws, size_t ws_size,
                              hipStream_t stream) {
    const float* x    = (const float*)d_in[0];
    const int*   ei   = (const int*)d_in[1];   // int32 [2, E]: row0 = src, row1 = dst
    const float* w    = (const float*)d_in[2];
    const float* bias = (const float*)d_in[3];
    float* out = (float*)d_out;

    int n_edges = in_sizes[1] / 2;
    int n_nodes = in_sizes[0] / D;
    const int* src = ei;
    const int* dst = ei + n_edges;

    // ws layout: h | deg_src | deg_dst | dis | rowptr | cursor | bsum | edata
    char* ws = (char*)d_ws;
    float* h       = (float*)ws;                       ws += (size_t)n_nodes * D * sizeof(float);
    int*   deg_src = (int*)ws;                         ws += (size_t)n_nodes * sizeof(int);
    int*   deg_dst = (int*)ws;                         ws += (size_t)n_nodes * sizeof(int);
    float* dis     = (float*)ws;                       ws += (size_t)n_nodes * sizeof(float);
    int*   rowptr  = (int*)ws;                         ws += (size_t)n_nodes * sizeof(int);
    int*   cursor  = (int*)ws;                         ws += (size_t)n_nodes * sizeof(int);
    int*   bsum    = (int*)ws;                         ws += 1024 * sizeof(int);
    int2*  edata   = (int2*)ws;

    int nbE = (n_edges + 255) / 256;
    int nbN = (n_nodes + 255) / 256;

    hipMemsetAsync(deg_src, 0, 2 * (size_t)n_nodes * sizeof(int), stream);  // deg_src+deg_dst adjacent
    k_hist<<<nbE, 256, 0, stream>>>(src, dst, deg_src, deg_dst, n_edges);
    k_dis<<<nbN, 256, 0, stream>>>(deg_src, dis, n_nodes);
    k_bsum<<<nbN, 256, 0, stream>>>(deg_dst, bsum, n_nodes);
    k_scanb<<<1, 512, 0, stream>>>(bsum, nbN);
    k_scanf<<<nbN, 256, 0, stream>>>(deg_dst, bsum, rowptr, cursor, n_nodes);
    k_bucket<<<nbE, 256, 0, stream>>>(src, dst, dis, cursor, edata, n_edges);
    k_gemm<<<(n_nodes + 63) / 64, 256, 0, stream>>>(x, w, h, n_nodes);
    k_accum<<<(n_nodes + 3) / 4, 256, 0, stream>>>(edata, rowptr, deg_dst, h, bias, out, n_nodes);
}